// Round 15
// baseline (42.125 us; speedup 1.0000x reference)
//
#include <hip/hip_runtime.h>
#include <hip/hip_fp16.h>
#include <math.h>

#define N_ATOMS 21
#define DESC 210
#define APAD 224            // padded descriptor length (7 x 32)
#define T_ROWS 12000
#define BATCH 64
#define NBLK 500            // fused blocks: 24 t each, 500*24 = 12000 EXACT
#define TROWS_B 24
#define PCW 216             // pC padded row (27 x 8 halfs)

#define QCONST 0.22360679774997896f   // sqrt(5)/10
#define K0CONST (1.0f/60.0f)          // 5/(3*sig^2)

typedef short bf16x8 __attribute__((ext_vector_type(8)));
typedef float f32x4 __attribute__((ext_vector_type(4)));

__device__ __forceinline__ float u2f(unsigned int u) {
    union { unsigned int u; float f; } x; x.u = u; return x.f;
}
__device__ __forceinline__ unsigned short f2bf(float f) {
    union { float f; unsigned int u; } x; x.f = f;
    unsigned int r = x.u + 0x7fffu + ((x.u >> 16) & 1u);  // RNE
    return (unsigned short)(r >> 16);
}
__device__ __forceinline__ float bf2f(unsigned short h) {
    return u2f((unsigned int)h << 16);
}

// ---------------- k_prep: Abf[m][224] = bf16(q/dist), na2 = ||bf16 row||^2 ----------------
__global__ __launch_bounds__(256) void k_prep(const float* __restrict__ Rs,
                                              unsigned short* __restrict__ Abf,
                                              float* __restrict__ na2) {
    int m = blockIdx.x;
    __shared__ float R[N_ATOMS * 3];
    __shared__ float red[256];
    int tid = threadIdx.x;
    if (tid < N_ATOMS * 3) R[tid] = Rs[m * N_ATOMS * 3 + tid];
    __syncthreads();
    float val = 0.f;
    if (tid < DESC) {
        int p = tid;
        int i = (int)((1.0f + sqrtf(1.0f + 8.0f * (float)p)) * 0.5f);
        while (i * (i - 1) / 2 > p) --i;
        while ((i + 1) * i / 2 <= p) ++i;
        int j = p - i * (i - 1) / 2;
        float dx = R[i * 3 + 0] - R[j * 3 + 0];
        float dy = R[i * 3 + 1] - R[j * 3 + 1];
        float dz = R[i * 3 + 2] - R[j * 3 + 2];
        float d = sqrtf(dx * dx + dy * dy + dz * dz);
        val = QCONST / d;
    }
    unsigned short h = f2bf(val);
    if (tid < APAD) Abf[m * APAD + tid] = h;
    float va = bf2f(h);
    red[tid] = va * va;
    __syncthreads();
    for (int s = 128; s > 0; s >>= 1) {
        if (tid < s) red[tid] += red[tid + s];
        __syncthreads();
    }
    if (tid == 0) na2[m] = red[0];
}

// ---------------- k_fused: stage + MFMA A + epilogue + MFMA C, 24 t/block ----------------
// 500 blocks x 256 thr (4 waves), 70 KB LDS -> 2 blocks/CU (8 waves/CU).
// Phase A: P=A.B^T, Q=A.J^T (wave = m-tile of 16; 2 t-tiles, rows 24..31 zeroed).
// Phase C: D[64m][224d] = W[64m][48k(+pad)] . X; K = {24 w1q|B rows, 24 w2|J rows}, k-pad zeroed.
// Frag maps (R7/R8-validated): A/B row|col=lane&15, k=(lane>>4)*8+e ;
// C/D col=lane&15, row=(lane>>4)*4+r.
#define BS_OFF 0        // 32 x 464 B (rows 24..31 zero); D [64][448 B] aliases 0..28671 later
#define JS_OFF 14848    // 32 x 464 B (rows 24..31 zero)
#define XT_OFF 29696    // 224 x 144 B (k 0..63 bf16, k>=48 zero, 16 B row pad)
#define W_OFF  61952    // 64 x 144 B  (k 0..63 bf16, k>=48 zero)
#define NB_OFF 71168    // 32 f32 (24..31 zero)
#define BJ_OFF 71296    // 32 f32
#define NA_OFF 71424    // 64 f32
#define LDS_SZ 71680    // 70 KB

__global__ __launch_bounds__(256) void k_fused(const float* __restrict__ Btr,
                                               const float* __restrict__ Jx,
                                               const unsigned short* __restrict__ Abf,
                                               const float* __restrict__ na2,
                                               float* __restrict__ es_p,  // [64][NBLK]
                                               float* __restrict__ rs_p,
                                               __half* __restrict__ pC) { // [m][blk][216]
    __shared__ char lds[LDS_SZ];
    const int blk = blockIdx.x;
    const int t0 = blk * TROWS_B;
    const int tid = threadIdx.x;
    const int lane = tid & 63;
    const int mt = __builtin_amdgcn_readfirstlane(tid >> 6);  // wave = m-tile 0..3
    const int lr = lane & 15;
    const int kb = lane >> 4;

    // A-frags hoisted to registers (L2-hot)
    uint4 au[7];
    {
        const unsigned short* ap = Abf + (mt * 16 + lr) * APAD + kb * 8;
#pragma unroll
        for (int k8 = 0; k8 < 7; k8++) au[k8] = *(const uint4*)(ap + k8 * 32);
    }
    if (tid < 64) *(float*)(lds + NA_OFF + tid * 4) = na2[tid];

    // ---- zero fills: BS/JS pad rows, XT/W k-pad, NB/BJ pad ----
    {
        const uint4 z = make_uint4(0, 0, 0, 0);
        for (int i = tid; i < 464; i += 256) {      // BS/JS rows 24..31 (29 uint4/row)
            const int arr = (i >= 232) ? 1 : 0;
            const int j = i - arr * 232;
            const int r = 24 + j / 29, c = j % 29;
            *(uint4*)(lds + (arr ? JS_OFF : BS_OFF) + r * 464 + c * 16) = z;
        }
        for (int i = tid; i < 448; i += 256) {      // XT k-pad (bytes 96..127 per row)
            const int d = i >> 1;
            *(uint4*)(lds + XT_OFF + d * 144 + 96 + (i & 1) * 16) = z;
        }
        if (tid < 128) {                            // W k-pad
            const int m = tid >> 1;
            *(uint4*)(lds + W_OFF + m * 144 + 96 + (tid & 1) * 16) = z;
        }
        if (tid < 16)                               // NB/BJ rows 24..31
            *(float*)(lds + (tid < 8 ? NB_OFF : BJ_OFF) + (24 + (tid & 7)) * 4) = 0.f;
    }

    // ---- stage: 48 row-tasks (24 B + 24 J) over 32 groups x 1.5 passes; 2-phase load ----
#pragma unroll
    for (int pass = 0; pass < 2; ++pass) {
        if (pass == 1 && tid >= 128) break;         // wave-uniform skip (waves 2,3)
        const int g = tid >> 3, gl = tid & 7;
        int arr, row;
        if (pass == 0) { arr = (g >= 24) ? 1 : 0; row = arr ? (g - 24) : g; }
        else           { arr = 1; row = 8 + g; }
        const float* sp = (arr ? Jx : Btr) + (size_t)(t0 + row) * DESC;
        float2 v[14];
#pragma unroll
        for (int it = 0; it < 14; ++it) {           // all loads issued unconditionally
            int c = it * 8 + gl; if (c > 104) c = 104;
            v[it] = *(const float2*)(sp + 2 * c);
        }
        char* const rdst = lds + (arr ? JS_OFF : BS_OFF) + row * 464;
        const int xtc = (arr ? 48 : 0) + row * 2;
#pragma unroll
        for (int it = 0; it < 14; ++it) {
            const int c = it * 8 + gl;              // <= 111
            const bool real = (c < 105);
            const float2 vv = real ? v[it] : make_float2(0.f, 0.f);
            const unsigned short hx = f2bf(vv.x), hy = f2bf(vv.y);
            *(unsigned int*)(rdst + c * 4) = (unsigned)hx | ((unsigned)hy << 16);
            if (real) {
                const int d = 2 * c;
                *(unsigned short*)(lds + XT_OFF + d * 144 + xtc) = hx;
                *(unsigned short*)(lds + XT_OFF + (d + 1) * 144 + xtc) = hy;
            }
        }
        if (gl < 4) *(unsigned int*)(rdst + (112 + gl) * 4) = 0u;  // granules 112..115
    }
    __syncthreads();

    // ---- nb/bj from staged bf16 rows (24 groups of 8; waves 0..2) ----
    if (tid < 192) {
        const int row = tid >> 3, gl = tid & 7;
        float nb = 0.f, bj = 0.f;
#pragma unroll
        for (int it = 0; it < 14; ++it) {
            const int c = it * 8 + gl;
            if (c < 105) {
                const unsigned int ub = *(const unsigned int*)(lds + BS_OFF + row * 464 + c * 4);
                const unsigned int uj = *(const unsigned int*)(lds + JS_OFF + row * 464 + c * 4);
                const float bx = u2f(ub << 16), by = u2f(ub & 0xFFFF0000u);
                const float jx2 = u2f(uj << 16), jy2 = u2f(uj & 0xFFFF0000u);
                nb = fmaf(bx, bx, nb); nb = fmaf(by, by, nb);
                bj = fmaf(bx, jx2, bj); bj = fmaf(by, jy2, bj);
            }
        }
#pragma unroll
        for (int msk = 1; msk < 8; msk <<= 1) { nb += __shfl_xor(nb, msk); bj += __shfl_xor(bj, msk); }
        if (gl == 0) {
            *(float*)(lds + NB_OFF + row * 4) = nb;
            *(float*)(lds + BJ_OFF + row * 4) = bj;
        }
    }

    // ---- phase A MFMA: 2 t-tiles (rows 0..15, 16..31) ----
    f32x4 accP[2] = {{0.f,0.f,0.f,0.f},{0.f,0.f,0.f,0.f}};
    f32x4 accQ[2] = {{0.f,0.f,0.f,0.f},{0.f,0.f,0.f,0.f}};
#pragma unroll
    for (int k8 = 0; k8 < 7; k8++) {
        union { uint4 u; bf16x8 h; } a;
        a.u = au[k8];
#pragma unroll
        for (int nt = 0; nt < 2; nt++) {
            union { uint4 u; bf16x8 h; } bu, ju;
            const int ro = (nt * 16 + lr) * 464 + k8 * 64 + kb * 16;
            bu.u = *(const uint4*)(lds + BS_OFF + ro);
            ju.u = *(const uint4*)(lds + JS_OFF + ro);
            accP[nt] = __builtin_amdgcn_mfma_f32_16x16x32_bf16(a.h, bu.h, accP[nt], 0, 0, 0);
            accQ[nt] = __builtin_amdgcn_mfma_f32_16x16x32_bf16(a.h, ju.h, accQ[nt], 0, 0, 0);
        }
    }
    __syncthreads();   // NB/BJ visible to all

    // ---- epilogue: w1q/w2 -> W (k=row / 24+row), es/rs (pad rows give dot=0) ----
    float na4[4];
#pragma unroll
    for (int r = 0; r < 4; r++)
        na4[r] = *(const float*)(lds + NA_OFF + (mt * 16 + kb * 4 + r) * 4);
    float es4[4] = {0.f,0.f,0.f,0.f}, rs4[4] = {0.f,0.f,0.f,0.f};
#pragma unroll
    for (int nt = 0; nt < 2; nt++) {
        const int row = nt * 16 + lr;
        const float nb_c = *(const float*)(lds + NB_OFF + row * 4);
        const float bj_c = *(const float*)(lds + BJ_OFF + row * 4);
#pragma unroll
        for (int r = 0; r < 4; r++) {
            float S = na4[r] + QCONST * QCONST * nb_c - 2.f * QCONST * accP[nt][r];
            float xd = sqrtf(fmaxf(S, 0.f));
            float e = K0CONST * __expf(-xd);
            float dot = accQ[nt][r] - QCONST * bj_c;   // zero rows -> dot = 0 exactly
            float w1 = e * dot;
            float w2 = e * (1.f + xd);
            es4[r] += w2 * dot; rs4[r] += w1;
            if (row < 24) {
                const int mrow = mt * 16 + kb * 4 + r;
                *(unsigned short*)(lds + W_OFF + mrow * 144 + row * 2) = f2bf(QCONST * w1);
                *(unsigned short*)(lds + W_OFF + mrow * 144 + 48 + row * 2) = f2bf(w2);
            }
        }
    }
#pragma unroll
    for (int msk = 1; msk < 16; msk <<= 1) {
#pragma unroll
        for (int r = 0; r < 4; r++) {
            es4[r] += __shfl_xor(es4[r], msk);
            rs4[r] += __shfl_xor(rs4[r], msk);
        }
    }
    if (lr == 0) {
#pragma unroll
        for (int r = 0; r < 4; r++) {
            es_p[(size_t)(mt * 16 + kb * 4 + r) * NBLK + blk] = es4[r];
            rs_p[(size_t)(mt * 16 + kb * 4 + r) * NBLK + blk] = rs4[r];
        }
    }
    __syncthreads();   // W complete; BS/JS dead -> D may alias

    // ---- phase C MFMA: D[m][d] = W[64x64k] . X (k>=48 zero); 14 d-tiles x 2 ----
    {
        union { uint4 u; bf16x8 h; } wa[2];
        const char* Wp = lds + W_OFF + (mt * 16 + lr) * 144;
#pragma unroll
        for (int c = 0; c < 2; c++) wa[c].u = *(const uint4*)(Wp + c * 64 + kb * 16);
        __half* D = (__half*)lds;                     // [64][224]
#pragma unroll
        for (int dt = 0; dt < 14; dt++) {
            const char* Xp = lds + XT_OFF + (dt * 16 + lr) * 144;
            f32x4 acc = {0.f, 0.f, 0.f, 0.f};
#pragma unroll
            for (int c = 0; c < 2; c++) {
                union { uint4 u; bf16x8 h; } xb;
                xb.u = *(const uint4*)(Xp + c * 64 + kb * 16);
                acc = __builtin_amdgcn_mfma_f32_16x16x32_bf16(wa[c].h, xb.h, acc, 0, 0, 0);
            }
#pragma unroll
            for (int r = 0; r < 4; r++)
                D[(mt * 16 + kb * 4 + r) * 224 + dt * 16 + lr] = __float2half(acc[r]);
        }
    }
    __syncthreads();

    // ---- coalesced pC store ----
    {
        const char* D = (const char*)lds;
        for (int i = tid; i < 64 * 27; i += 256) {
            const int mrow = i / 27, oct = i % 27;
            uint4 v = *(const uint4*)(D + mrow * 448 + oct * 16);
            *(uint4*)((char*)pC + (((size_t)mrow * NBLK + blk) * PCW + oct * 8) * 2) = v;
        }
    }
}

// ---------------- k_final: streaming c-reduction, rank-1 term, force contraction ----------------
__global__ __launch_bounds__(512) void k_final(const float* __restrict__ Rs,
                                               const unsigned short* __restrict__ Abf,
                                               const float* __restrict__ es_p,
                                               const float* __restrict__ rs_p,
                                               const __half* __restrict__ pC,
                                               float* __restrict__ out) {
    const int m = blockIdx.x;
    const int tid = threadIdx.x;
    __shared__ float parts[27][16][8];   // [octet][c-group][elem]
    __shared__ float fsx[DESC];
    __shared__ float R[N_ATOMS * 3];
    __shared__ float s_rs, s_es;
    if (tid < N_ATOMS * 3) R[tid] = Rs[m * N_ATOMS * 3 + tid];
    if (tid < 432) {   // 16 c-groups x 27 octets, coalesced uint4 streams
        const int cg = tid / 27, o = tid % 27;
        float facc[8];
#pragma unroll
        for (int e = 0; e < 8; e++) facc[e] = 0.f;
        const __half* base = pC + (size_t)m * NBLK * PCW + o * 8;
        for (int c = cg; c < NBLK; c += 16) {
            uint4 v = *(const uint4*)(base + (size_t)c * PCW);
            const __half2* h = (const __half2*)&v;
#pragma unroll
            for (int p2 = 0; p2 < 4; p2++) {
                float2 f = __half22float2(h[p2]);
                facc[p2 * 2] += f.x;
                facc[p2 * 2 + 1] += f.y;
            }
        }
#pragma unroll
        for (int e = 0; e < 8; e++) parts[o][cg][e] = facc[e];
    } else if (tid >= 448) {   // wave 7: es/rs contiguous reduce
        const int lx = tid - 448;
        float es = 0.f, rs = 0.f;
        for (int c2 = lx; c2 < NBLK; c2 += 64) {
            es += es_p[(size_t)m * NBLK + c2];
            rs += rs_p[(size_t)m * NBLK + c2];
        }
        for (int msk = 1; msk < 64; msk <<= 1) {
            es += __shfl_xor(es, msk);
            rs += __shfl_xor(rs, msk);
        }
        if (lx == 0) { s_es = es; s_rs = rs; }
    }
    __syncthreads();
    if (tid < DESC) {
        float s = 0.f;
        const int o = tid >> 3, e = tid & 7;
#pragma unroll
        for (int cg = 0; cg < 16; cg++) s += parts[o][cg][e];
        fsx[tid] = s_rs * bf2f(Abf[m * APAD + tid]) - s;  // STD = 1
    }
    if (tid == 0) out[m] = s_es * (1.0f / QCONST);        // Es = sum/q, C=0
    __syncthreads();
    if (tid < N_ATOMS * 3) {
        const int b = tid / 3, kk = tid % 3;
        float acc = 0.f;
        for (int a = 0; a < N_ATOMS; a++) {
            if (a == b) continue;
            float dx = R[a * 3 + 0] - R[b * 3 + 0];
            float dy = R[a * 3 + 1] - R[b * 3 + 1];
            float dz = R[a * 3 + 2] - R[b * 3 + 2];
            float d2 = dx * dx + dy * dy + dz * dz;
            float dist = sqrtf(d2);
            float inv3 = 1.0f / (d2 * dist);
            int hi = (a > b) ? a : b, lo = (a > b) ? b : a;
            int p = hi * (hi - 1) / 2 + lo;
            float diffk = (kk == 0) ? dx : ((kk == 1) ? dy : dz);
            acc = fmaf(fsx[p] * inv3, diffk, acc);
        }
        out[BATCH + m * N_ATOMS * 3 + tid] = acc;
    }
}

extern "C" void kernel_launch(void* const* d_in, const int* in_sizes, int n_in,
                              void* d_out, int out_size, void* d_ws, size_t ws_size,
                              hipStream_t stream) {
    (void)in_sizes; (void)n_in; (void)out_size; (void)ws_size;
    const float* Rs = (const float*)d_in[0];
    const float* Btr = (const float*)d_in[1];
    const float* Jx = (const float*)d_in[2];
    float* out = (float*)d_out;

    char* ws = (char*)d_ws;
    unsigned short* Abf = (unsigned short*)ws;  ws += (size_t)BATCH * APAD * 2;   // 28.7 KB
    float* na2 = (float*)ws;                    ws += BATCH * 4;
    float* es_p = (float*)ws;                   ws += (size_t)BATCH * NBLK * 4;   // 128 KB
    float* rs_p = (float*)ws;                   ws += (size_t)BATCH * NBLK * 4;   // 128 KB
    __half* pC = (__half*)ws;                   // 64*500*216*2 = 13.8 MB, [m][blk][d]

    k_prep<<<dim3(BATCH), dim3(256), 0, stream>>>(Rs, Abf, na2);
    k_fused<<<dim3(NBLK), dim3(256), 0, stream>>>(Btr, Jx, Abf, na2, es_p, rs_p, pC);
    k_final<<<dim3(BATCH), dim3(512), 0, stream>>>(Rs, Abf, es_p, rs_p, pC, out);
}

// Round 16
// 32.433 us; speedup vs baseline: 1.2989x; 1.2989x over previous
//
#include <hip/hip_runtime.h>
#include <hip/hip_fp16.h>
#include <math.h>

#define N_ATOMS 21
#define DESC 210
#define APAD 224            // padded descriptor length (7 x 32)
#define T_ROWS 12000
#define BATCH 64
#define NBLK 250            // fused blocks: 48 t each, 250*48 = 12000 EXACT
#define TROWS_B 48
#define PCW 216             // pC padded row (27 x 8 halfs)

#define QCONST 0.22360679774997896f   // sqrt(5)/10
#define K0CONST (1.0f/60.0f)          // 5/(3*sig^2)

typedef short bf16x8 __attribute__((ext_vector_type(8)));
typedef float f32x4 __attribute__((ext_vector_type(4)));

__device__ __forceinline__ float u2f(unsigned int u) {
    union { unsigned int u; float f; } x; x.u = u; return x.f;
}
__device__ __forceinline__ unsigned short f2bf(float f) {
    union { float f; unsigned int u; } x; x.f = f;
    unsigned int r = x.u + 0x7fffu + ((x.u >> 16) & 1u);  // RNE
    return (unsigned short)(r >> 16);
}
__device__ __forceinline__ float bf2f(unsigned short h) {
    return u2f((unsigned int)h << 16);
}

// ---------------- k_prep: Abf[m][224] = bf16(q/dist), na2 = ||bf16 row||^2 ----------------
__global__ __launch_bounds__(256) void k_prep(const float* __restrict__ Rs,
                                              unsigned short* __restrict__ Abf,
                                              float* __restrict__ na2) {
    int m = blockIdx.x;
    __shared__ float R[N_ATOMS * 3];
    __shared__ float red[256];
    int tid = threadIdx.x;
    if (tid < N_ATOMS * 3) R[tid] = Rs[m * N_ATOMS * 3 + tid];
    __syncthreads();
    float val = 0.f;
    if (tid < DESC) {
        int p = tid;
        int i = (int)((1.0f + sqrtf(1.0f + 8.0f * (float)p)) * 0.5f);
        while (i * (i - 1) / 2 > p) --i;
        while ((i + 1) * i / 2 <= p) ++i;
        int j = p - i * (i - 1) / 2;
        float dx = R[i * 3 + 0] - R[j * 3 + 0];
        float dy = R[i * 3 + 1] - R[j * 3 + 1];
        float dz = R[i * 3 + 2] - R[j * 3 + 2];
        float d = sqrtf(dx * dx + dy * dy + dz * dz);
        val = QCONST / d;
    }
    unsigned short h = f2bf(val);
    if (tid < APAD) Abf[m * APAD + tid] = h;
    float va = bf2f(h);
    red[tid] = va * va;
    __syncthreads();
    for (int s = 128; s > 0; s >>= 1) {
        if (tid < s) red[tid] += red[tid + s];
        __syncthreads();
    }
    if (tid == 0) na2[m] = red[0];
}

// ---------------- k_fused: stage + MFMA A + epilogue + MFMA C, 48 t/block, 8 waves ----------------
// 250 blocks x 512 thr (8 waves = 2/SIMD), 104 KB LDS -> 1 block/CU.
// Phase A: P=A.B^T, Q=A.J^T; 12 (m-tile, t-tile) tasks over 8 waves.
// Phase C: D[64m][224d] = W[64m][96k] . X[96k][224d]; wave = (m-tile, d-half).
// Frag maps (R7/R8-validated): A/B row|col=lane&15, k=(lane>>4)*8+e ;
// C/D col=lane&15, row=(lane>>4)*4+r.
#define BS_OFF 0        // 48 x 464 B  (B rows bf16; D [64][448 B] aliases BS/JS later)
#define JS_OFF 22272    // 48 x 464 B
#define XT_OFF 44544    // 224 x 208 B (X^T: row d, 96 k-cols bf16 + 16 B pad)
#define W_OFF  91136    // 64 x 208 B  (W: row m, 96 k-cols bf16 + pad)
#define NB_OFF 104448   // 48 f32
#define BJ_OFF 104640   // 48 f32
#define NA_OFF 104832   // 64 f32
#define ES_OFF 105088   // es [3][64] f32 ; rs at +768
#define LDS_SZ 106624

__global__ __launch_bounds__(512) void k_fused(const float* __restrict__ Btr,
                                               const float* __restrict__ Jx,
                                               const unsigned short* __restrict__ Abf,
                                               const float* __restrict__ na2,
                                               float* __restrict__ es_p,  // [64][NBLK]
                                               float* __restrict__ rs_p,
                                               __half* __restrict__ pC) { // [m][blk][216]
    __shared__ char lds[LDS_SZ];
    const int blk = blockIdx.x;
    const int t0 = blk * TROWS_B;
    const int tid = threadIdx.x;
    const int lane = tid & 63;
    const int w = __builtin_amdgcn_readfirstlane(tid >> 6);  // wave 0..7
    const int lr = lane & 15;
    const int kb = lane >> 4;
    const int mt = w & 3;        // m-tile
    const int half = w >> 2;     // t-tile / d-half split

    // A-frags hoisted to registers (L2-hot global)
    uint4 au[7];
    {
        const unsigned short* ap = Abf + (mt * 16 + lr) * APAD + kb * 8;
#pragma unroll
        for (int k8 = 0; k8 < 7; k8++) au[k8] = *(const uint4*)(ap + k8 * 32);
    }
    if (tid < 64) *(float*)(lds + NA_OFF + tid * 4) = na2[tid];

    // ---- stage: 96 row-tasks (48 B + 48 J), 64 groups x 1.5 passes, two-phase loads ----
#pragma unroll
    for (int pass = 0; pass < 2; ++pass) {
        if (pass == 1 && tid >= 256) break;        // wave-uniform skip (waves 4..7)
        const int g = tid >> 3, gl = tid & 7;
        int arr, row;
        if (pass == 0) { arr = (g >= 48) ? 1 : 0; row = arr ? (g - 48) : g; }
        else           { arr = 1; row = 16 + g; }
        const float* sp = (arr ? Jx : Btr) + (size_t)(t0 + row) * DESC;
        float2 v[14];
#pragma unroll
        for (int it = 0; it < 14; ++it) {          // all loads issued up-front (clamped)
            int c = it * 8 + gl; if (c > 104) c = 104;
            v[it] = *(const float2*)(sp + 2 * c);
        }
        char* const rdst = lds + (arr ? JS_OFF : BS_OFF) + row * 464;
        const int xtc = (arr ? 96 : 0) + row * 2;
#pragma unroll
        for (int it = 0; it < 14; ++it) {
            const int c = it * 8 + gl;             // 0..111
            const bool real = (c < 105);
            const float2 vv = real ? v[it] : make_float2(0.f, 0.f);
            const unsigned short hx = f2bf(vv.x), hy = f2bf(vv.y);
            *(unsigned int*)(rdst + c * 4) = (unsigned)hx | ((unsigned)hy << 16);
            if (c < 112) {                         // XT rows d=0..223 (zeros for d>=210)
                const int d = 2 * c;
                *(unsigned short*)(lds + XT_OFF + d * 208 + xtc) = hx;
                *(unsigned short*)(lds + XT_OFF + (d + 1) * 208 + xtc) = hy;
            }
        }
        if (gl < 4) *(unsigned int*)(rdst + (112 + gl) * 4) = 0u;  // granules 112..115
    }
    __syncthreads();

    // ---- nb/bj from staged bf16 rows (48 groups x 8 lanes; waves 0..5) ----
    if (tid < 384) {
        const int row = tid >> 3, gl = tid & 7;
        float nb = 0.f, bj = 0.f;
#pragma unroll
        for (int it = 0; it < 14; ++it) {
            const int c = it * 8 + gl;
            if (c < 105) {
                const unsigned int ub = *(const unsigned int*)(lds + BS_OFF + row * 464 + c * 4);
                const unsigned int uj = *(const unsigned int*)(lds + JS_OFF + row * 464 + c * 4);
                const float bx = u2f(ub << 16), by = u2f(ub & 0xFFFF0000u);
                const float jx2 = u2f(uj << 16), jy2 = u2f(uj & 0xFFFF0000u);
                nb = fmaf(bx, bx, nb); nb = fmaf(by, by, nb);
                bj = fmaf(bx, jx2, bj); bj = fmaf(by, jy2, bj);
            }
        }
#pragma unroll
        for (int msk = 1; msk < 8; msk <<= 1) { nb += __shfl_xor(nb, msk); bj += __shfl_xor(bj, msk); }
        if (gl == 0) {
            *(float*)(lds + NB_OFF + row * 4) = nb;
            *(float*)(lds + BJ_OFF + row * 4) = bj;
        }
    }

    // ---- phase A MFMA: wave half 0 -> t-tile 0 ; half 1 -> t-tiles 1,2 ----
    const int nt0 = (half == 0) ? 0 : 1;
    const int nnt = (half == 0) ? 1 : 2;
    f32x4 accP[2] = {{0.f,0.f,0.f,0.f},{0.f,0.f,0.f,0.f}};
    f32x4 accQ[2] = {{0.f,0.f,0.f,0.f},{0.f,0.f,0.f,0.f}};
#pragma unroll
    for (int k8 = 0; k8 < 7; k8++) {
        union { uint4 u; bf16x8 h; } a;
        a.u = au[k8];
#pragma unroll
        for (int s = 0; s < 2; s++) {
            if (s < nnt) {
                const int nt = nt0 + s;
                union { uint4 u; bf16x8 h; } bu, ju;
                const int ro = (nt * 16 + lr) * 464 + k8 * 64 + kb * 16;
                bu.u = *(const uint4*)(lds + BS_OFF + ro);
                ju.u = *(const uint4*)(lds + JS_OFF + ro);
                accP[s] = __builtin_amdgcn_mfma_f32_16x16x32_bf16(a.h, bu.h, accP[s], 0, 0, 0);
                accQ[s] = __builtin_amdgcn_mfma_f32_16x16x32_bf16(a.h, ju.h, accQ[s], 0, 0, 0);
            }
        }
    }
    __syncthreads();   // NB/BJ visible

    // ---- epilogue: w1q/w2 -> W (bf16 LDS), es/rs partials -> ES LDS ----
    float na4[4];
#pragma unroll
    for (int r = 0; r < 4; r++)
        na4[r] = *(const float*)(lds + NA_OFF + (mt * 16 + kb * 4 + r) * 4);
#pragma unroll
    for (int s = 0; s < 2; s++) {
        if (s < nnt) {
            const int nt = nt0 + s;
            const int row = nt * 16 + lr;
            const float nb_c = *(const float*)(lds + NB_OFF + row * 4);
            const float bj_c = *(const float*)(lds + BJ_OFF + row * 4);
            float es4[4], rs4[4];
#pragma unroll
            for (int r = 0; r < 4; r++) {
                float S = na4[r] + QCONST * QCONST * nb_c - 2.f * QCONST * accP[s][r];
                float xd = sqrtf(fmaxf(S, 0.f));
                float e = K0CONST * __expf(-xd);
                float dot = accQ[s][r] - QCONST * bj_c;
                float w1 = e * dot;
                float w2 = e * (1.f + xd);
                es4[r] = w2 * dot; rs4[r] = w1;
                const int mrow = mt * 16 + kb * 4 + r;
                *(unsigned short*)(lds + W_OFF + mrow * 208 + row * 2) = f2bf(QCONST * w1);
                *(unsigned short*)(lds + W_OFF + mrow * 208 + 96 + row * 2) = f2bf(w2);
            }
#pragma unroll
            for (int msk = 1; msk < 16; msk <<= 1) {
#pragma unroll
                for (int r = 0; r < 4; r++) {
                    es4[r] += __shfl_xor(es4[r], msk);
                    rs4[r] += __shfl_xor(rs4[r], msk);
                }
            }
            if (lr == 0) {
#pragma unroll
                for (int r = 0; r < 4; r++) {
                    const int m = mt * 16 + kb * 4 + r;
                    *(float*)(lds + ES_OFF + (nt * 64 + m) * 4) = es4[r];
                    *(float*)(lds + ES_OFF + 768 + (nt * 64 + m) * 4) = rs4[r];
                }
            }
        }
    }
    __syncthreads();   // W + ES complete; BS/JS dead -> D may alias

    // ---- es/rs global store (concurrent with phase C) ----
    if (tid < 64) {
        const float* esl = (const float*)(lds + ES_OFF);
        const float* rsl = (const float*)(lds + ES_OFF + 768);
        es_p[(size_t)tid * NBLK + blk] = esl[tid] + esl[64 + tid] + esl[128 + tid];
        rs_p[(size_t)tid * NBLK + blk] = rsl[tid] + rsl[64 + tid] + rsl[128 + tid];
    }

    // ---- phase C MFMA: D[m][d] = W[64x96] . X[96x224]; wave: (m-tile, d-half) ----
    {
        union { uint4 u; bf16x8 h; } wa[3];
        const char* Wp = lds + W_OFF + (mt * 16 + lr) * 208;
#pragma unroll
        for (int c = 0; c < 3; c++) wa[c].u = *(const uint4*)(Wp + c * 64 + kb * 16);
        __half* D = (__half*)lds;                     // [64][224]
#pragma unroll
        for (int j = 0; j < 7; j++) {
            const int dt = half * 7 + j;
            const char* Xp = lds + XT_OFF + (dt * 16 + lr) * 208;
            f32x4 acc = {0.f, 0.f, 0.f, 0.f};
#pragma unroll
            for (int c = 0; c < 3; c++) {
                union { uint4 u; bf16x8 h; } xb;
                xb.u = *(const uint4*)(Xp + c * 64 + kb * 16);
                acc = __builtin_amdgcn_mfma_f32_16x16x32_bf16(wa[c].h, xb.h, acc, 0, 0, 0);
            }
#pragma unroll
            for (int r = 0; r < 4; r++)
                D[(mt * 16 + kb * 4 + r) * 224 + dt * 16 + lr] = __float2half(acc[r]);
        }
    }
    __syncthreads();

    // ---- coalesced pC store ----
    {
        const char* D = (const char*)lds;
        for (int i = tid; i < 64 * 27; i += 512) {
            const int mrow = i / 27, oct = i % 27;
            uint4 v = *(const uint4*)(D + mrow * 448 + oct * 16);
            *(uint4*)((char*)pC + (((size_t)mrow * NBLK + blk) * PCW + oct * 8) * 2) = v;
        }
    }
}

// ---------------- k_final: streaming c-reduction, rank-1 term, force contraction ----------------
__global__ __launch_bounds__(512) void k_final(const float* __restrict__ Rs,
                                               const unsigned short* __restrict__ Abf,
                                               const float* __restrict__ es_p,
                                               const float* __restrict__ rs_p,
                                               const __half* __restrict__ pC,
                                               float* __restrict__ out) {
    const int m = blockIdx.x;
    const int tid = threadIdx.x;
    __shared__ float parts[27][16][8];   // [octet][c-group][elem]
    __shared__ float fsx[DESC];
    __shared__ float R[N_ATOMS * 3];
    __shared__ float s_rs, s_es;
    if (tid < N_ATOMS * 3) R[tid] = Rs[m * N_ATOMS * 3 + tid];
    if (tid < 432) {   // 16 c-groups x 27 octets, coalesced uint4 streams
        const int cg = tid / 27, o = tid % 27;
        float facc[8];
#pragma unroll
        for (int e = 0; e < 8; e++) facc[e] = 0.f;
        const __half* base = pC + (size_t)m * NBLK * PCW + o * 8;
        for (int c = cg; c < NBLK; c += 16) {
            uint4 v = *(const uint4*)(base + (size_t)c * PCW);
            const __half2* h = (const __half2*)&v;
#pragma unroll
            for (int p2 = 0; p2 < 4; p2++) {
                float2 f = __half22float2(h[p2]);
                facc[p2 * 2] += f.x;
                facc[p2 * 2 + 1] += f.y;
            }
        }
#pragma unroll
        for (int e = 0; e < 8; e++) parts[o][cg][e] = facc[e];
    } else if (tid >= 448) {   // wave 7: es/rs contiguous reduce
        const int lx = tid - 448;
        float es = 0.f, rs = 0.f;
        for (int c2 = lx; c2 < NBLK; c2 += 64) {
            es += es_p[(size_t)m * NBLK + c2];
            rs += rs_p[(size_t)m * NBLK + c2];
        }
        for (int msk = 1; msk < 64; msk <<= 1) {
            es += __shfl_xor(es, msk);
            rs += __shfl_xor(rs, msk);
        }
        if (lx == 0) { s_es = es; s_rs = rs; }
    }
    __syncthreads();
    if (tid < DESC) {
        float s = 0.f;
        const int o = tid >> 3, e = tid & 7;
#pragma unroll
        for (int cg = 0; cg < 16; cg++) s += parts[o][cg][e];
        fsx[tid] = s_rs * bf2f(Abf[m * APAD + tid]) - s;  // STD = 1
    }
    if (tid == 0) out[m] = s_es * (1.0f / QCONST);        // Es = sum/q, C=0
    __syncthreads();
    if (tid < N_ATOMS * 3) {
        const int b = tid / 3, kk = tid % 3;
        float acc = 0.f;
        for (int a = 0; a < N_ATOMS; a++) {
            if (a == b) continue;
            float dx = R[a * 3 + 0] - R[b * 3 + 0];
            float dy = R[a * 3 + 1] - R[b * 3 + 1];
            float dz = R[a * 3 + 2] - R[b * 3 + 2];
            float d2 = dx * dx + dy * dy + dz * dz;
            float dist = sqrtf(d2);
            float inv3 = 1.0f / (d2 * dist);
            int hi = (a > b) ? a : b, lo = (a > b) ? b : a;
            int p = hi * (hi - 1) / 2 + lo;
            float diffk = (kk == 0) ? dx : ((kk == 1) ? dy : dz);
            acc = fmaf(fsx[p] * inv3, diffk, acc);
        }
        out[BATCH + m * N_ATOMS * 3 + tid] = acc;
    }
}

extern "C" void kernel_launch(void* const* d_in, const int* in_sizes, int n_in,
                              void* d_out, int out_size, void* d_ws, size_t ws_size,
                              hipStream_t stream) {
    (void)in_sizes; (void)n_in; (void)out_size; (void)ws_size;
    const float* Rs = (const float*)d_in[0];
    const float* Btr = (const float*)d_in[1];
    const float* Jx = (const float*)d_in[2];
    float* out = (float*)d_out;

    char* ws = (char*)d_ws;
    unsigned short* Abf = (unsigned short*)ws;  ws += (size_t)BATCH * APAD * 2;   // 28.7 KB
    float* na2 = (float*)ws;                    ws += BATCH * 4;
    float* es_p = (float*)ws;                   ws += (size_t)BATCH * NBLK * 4;   // 64 KB
    float* rs_p = (float*)ws;                   ws += (size_t)BATCH * NBLK * 4;   // 64 KB
    __half* pC = (__half*)ws;                   // 64*250*216*2 = 6.9 MB, [m][blk][d]

    k_prep<<<dim3(BATCH), dim3(256), 0, stream>>>(Rs, Abf, na2);
    k_fused<<<dim3(NBLK), dim3(512), 0, stream>>>(Btr, Jx, Abf, na2, es_p, rs_p, pC);
    k_final<<<dim3(BATCH), dim3(512), 0, stream>>>(Rs, Abf, es_p, rs_p, pC, out);
}